// Round 1
// baseline (4713.567 us; speedup 1.0000x reference)
//
#include <hip/hip_runtime.h>

#define DIM 1536
#define NHEADS 12
#define HD 128
#define MAX_ATTN_WIN 5632
#define RMS_EPS 1e-6f

// ==================== generic GEMM: C = A(MxK) * B(NxK)^T + bias ====================
#define BM 128
#define BN 128
#define BK 16

__global__ __launch_bounds__(256)
void gemm_bias_kernel(const float* __restrict__ A, const float* __restrict__ B,
                      const float* __restrict__ bias, float* __restrict__ C,
                      int M, int N, int K)
{
    __shared__ float As[BK][BM];
    __shared__ float Bs[BK][BN];
    const int tid = threadIdx.x;
    const int tx = tid & 15;
    const int ty = tid >> 4;
    const int m0 = blockIdx.y * BM;
    const int n0 = blockIdx.x * BN;

    float acc[8][8];
    #pragma unroll
    for (int i = 0; i < 8; ++i)
        #pragma unroll
        for (int j = 0; j < 8; ++j) acc[i][j] = 0.f;

    for (int k0 = 0; k0 < K; k0 += BK) {
        #pragma unroll
        for (int jj = 0; jj < 2; ++jj) {
            int lin = (jj << 8) + tid;     // 0..511
            int row = lin >> 2;            // 0..127
            int kq  = (lin & 3) << 2;      // 0,4,8,12
            int gm = m0 + row;
            float4 a = (gm < M) ? *(const float4*)&A[(size_t)gm * K + k0 + kq]
                                : make_float4(0.f, 0.f, 0.f, 0.f);
            As[kq + 0][row] = a.x; As[kq + 1][row] = a.y;
            As[kq + 2][row] = a.z; As[kq + 3][row] = a.w;
            float4 b = *(const float4*)&B[(size_t)(n0 + row) * K + k0 + kq];
            Bs[kq + 0][row] = b.x; Bs[kq + 1][row] = b.y;
            Bs[kq + 2][row] = b.z; Bs[kq + 3][row] = b.w;
        }
        __syncthreads();
        #pragma unroll
        for (int kk = 0; kk < BK; ++kk) {
            float4 a0 = *(const float4*)&As[kk][ty << 3];
            float4 a1 = *(const float4*)&As[kk][(ty << 3) + 4];
            float4 b0 = *(const float4*)&Bs[kk][tx << 3];
            float4 b1 = *(const float4*)&Bs[kk][(tx << 3) + 4];
            float av[8] = {a0.x, a0.y, a0.z, a0.w, a1.x, a1.y, a1.z, a1.w};
            float bv[8] = {b0.x, b0.y, b0.z, b0.w, b1.x, b1.y, b1.z, b1.w};
            #pragma unroll
            for (int i = 0; i < 8; ++i)
                #pragma unroll
                for (int j = 0; j < 8; ++j)
                    acc[i][j] = fmaf(av[i], bv[j], acc[i][j]);
        }
        __syncthreads();
    }

    #pragma unroll
    for (int i = 0; i < 8; ++i) {
        int gm = m0 + (ty << 3) + i;
        if (gm < M) {
            int gn = n0 + (tx << 3);
            float4 bb0 = *(const float4*)&bias[gn];
            float4 bb1 = *(const float4*)&bias[gn + 4];
            float4 o0 = make_float4(acc[i][0] + bb0.x, acc[i][1] + bb0.y,
                                    acc[i][2] + bb0.z, acc[i][3] + bb0.w);
            float4 o1 = make_float4(acc[i][4] + bb1.x, acc[i][5] + bb1.y,
                                    acc[i][6] + bb1.z, acc[i][7] + bb1.w);
            *(float4*)&C[(size_t)gm * N + gn]     = o0;
            *(float4*)&C[(size_t)gm * N + gn + 4] = o1;
        }
    }
}

// ==================== fused RMSNorm + RoPE (in-place, one block per token) ====================
__global__ __launch_bounds__(256)
void rmsnorm_rope_kernel(float* __restrict__ qbuf, float* __restrict__ kbuf,
                         const float* __restrict__ gq, const float* __restrict__ gk,
                         const float* __restrict__ theta,
                         const int* __restrict__ p_gh, const int* __restrict__ p_gw,
                         const int* __restrict__ p_cs, int S)
{
    const int s = blockIdx.x;
    float* row = ((blockIdx.y == 0) ? qbuf : kbuf) + (size_t)s * DIM;
    const float* g = (blockIdx.y == 0) ? gq : gk;
    const int tid = threadIdx.x;

    float v[6];
    #pragma unroll
    for (int i = 0; i < 6; ++i) v[i] = row[tid * 6 + i];
    float ss = 0.f;
    #pragma unroll
    for (int i = 0; i < 6; ++i) ss += v[i] * v[i];
    #pragma unroll
    for (int off = 32; off > 0; off >>= 1) ss += __shfl_xor(ss, off, 64);

    __shared__ float red[4];
    if ((tid & 63) == 0) red[tid >> 6] = ss;
    __syncthreads();
    float tot = red[0] + red[1] + red[2] + red[3];
    float rs = rsqrtf(tot * (1.0f / DIM) + RMS_EPS);

    const int H = p_gh[0], W = p_gw[0];
    const int fs = p_cs[0] / (H * W);       // start_frame
    const int fr = s / (H * W);
    const int rem = s - fr * (H * W);
    const int hh = rem / W;
    const int ww = rem - hh * W;

    #pragma unroll
    for (int pi = 0; pi < 3; ++pi) {
        int p = tid * 3 + pi;               // pair index 0..767
        int j = p & 63;                     // within-head pair 0..63
        float xr = v[pi * 2]     * rs * g[tid * 6 + pi * 2];
        float xi = v[pi * 2 + 1] * rs * g[tid * 6 + pi * 2 + 1];
        int rowi = (j < 22) ? (fs + fr) : ((j < 43) ? hh : ww);
        float ang = theta[rowi * 64 + j];
        float sn, cs;
        sincosf(ang, &sn, &cs);
        row[tid * 6 + pi * 2]     = xr * cs - xi * sn;
        row[tid * 6 + pi * 2 + 1] = xr * sn + xi * cs;
    }
}

// ==================== flash attention, fp32, 64q x 64k tiles, 64 KB LDS ====================
#define TQ 64
#define TK 64
#define KBASE 8192          // K region (S phase); P region overlaps its first 4096 floats
#define PBASE 8192

__global__ __launch_bounds__(256)
void attn_kernel(const float* __restrict__ rq, const float* __restrict__ rk,
                 const float* __restrict__ vnew,
                 const float* __restrict__ cache_k, const float* __restrict__ cache_v,
                 float* __restrict__ obuf,
                 const int* __restrict__ p_cs, const int* __restrict__ p_ge,
                 const int* __restrict__ p_le, int S)
{
    __shared__ float lds[16384];   // 64 KB: phase1 Q[0,8192)+K[8192,16384); phase2 V[0,8192)+P[8192,12288)
    const int tid = threadIdx.x;
    const int tx = tid & 15;
    const int ty = tid >> 4;
    const int h = blockIdx.y;
    const int hoff = h * HD;
    const int q0 = blockIdx.x * TQ;

    const int cur = p_cs[0];
    const int local_end = p_le[0] + (cur + S) - p_ge[0];
    const int local_start = local_end - S;
    int win_start = local_end - MAX_ATTN_WIN;
    if (win_start < 0) win_start = 0;
    const int L = local_end - win_start;

    float m_i[4], l_i[4], O[4][8];
    #pragma unroll
    for (int i = 0; i < 4; ++i) {
        m_i[i] = -1e30f; l_i[i] = 0.f;
        #pragma unroll
        for (int j = 0; j < 8; ++j) O[i][j] = 0.f;
    }

    const int ntiles = (L + TK - 1) / TK;
    for (int t = 0; t < ntiles; ++t) {
        __syncthreads();   // B1: prior PV reads done; safe to overwrite Q/K regions
        // stage Q (transposed+swizzled) and K (transposed+swizzled)
        #pragma unroll
        for (int i = 0; i < 8; ++i) {
            int cid = (i << 8) + tid;
            int d  = cid & 127;
            int c4 = cid >> 7;              // 16B chunk (4 consecutive q or k rows)
            float qt[4], kt[4];
            #pragma unroll
            for (int r = 0; r < 4; ++r) {
                int q = q0 + (c4 << 2) + r;
                qt[r] = (q < S) ? rq[(size_t)q * DIM + hoff + d] : 0.f;
                int kg = (t << 6) + (c4 << 2) + r;
                float xv = 0.f;
                if (kg < L) {
                    int pos = win_start + kg;
                    xv = (pos < local_start)
                        ? cache_k[(size_t)pos * DIM + hoff + d]
                        : rk[(size_t)(pos - local_start) * DIM + hoff + d];
                }
                kt[r] = xv;
            }
            int sw = (c4 ^ (d & 15)) << 2;
            *(float4*)&lds[d * 64 + sw]         = make_float4(qt[0], qt[1], qt[2], qt[3]);
            *(float4*)&lds[KBASE + d * 64 + sw] = make_float4(kt[0], kt[1], kt[2], kt[3]);
        }
        __syncthreads();   // B2
        // S = Q.K^T  (thread: 4q x 4k)
        float sacc[4][4];
        #pragma unroll
        for (int i = 0; i < 4; ++i)
            #pragma unroll
            for (int j = 0; j < 4; ++j) sacc[i][j] = 0.f;
        #pragma unroll 8
        for (int d = 0; d < HD; ++d) {
            float4 qv = *(const float4*)&lds[d * 64 + ((ty ^ (d & 15)) << 2)];
            float4 kv = *(const float4*)&lds[KBASE + d * 64 + ((tx ^ (d & 15)) << 2)];
            float qa[4] = {qv.x, qv.y, qv.z, qv.w};
            float ka[4] = {kv.x, kv.y, kv.z, kv.w};
            #pragma unroll
            for (int i = 0; i < 4; ++i)
                #pragma unroll
                for (int j = 0; j < 4; ++j)
                    sacc[i][j] = fmaf(qa[i], ka[j], sacc[i][j]);
        }
        // online softmax (rows live in 16 consecutive lanes: reduce via shfl_xor 1..8)
        const float scale = 0.088388347648318447f;   // 1/sqrt(128)
        float pp[4][4];
        #pragma unroll
        for (int i = 0; i < 4; ++i) {
            float sv[4];
            #pragma unroll
            for (int j = 0; j < 4; ++j) {
                int kg = (t << 6) + (tx << 2) + j;
                sv[j] = (kg < L) ? sacc[i][j] * scale : -1e30f;
            }
            float mx = fmaxf(fmaxf(sv[0], sv[1]), fmaxf(sv[2], sv[3]));
            #pragma unroll
            for (int off = 1; off < 16; off <<= 1)
                mx = fmaxf(mx, __shfl_xor(mx, off, 64));
            float mnew = fmaxf(m_i[i], mx);
            float alpha = __expf(m_i[i] - mnew);
            float rsum = 0.f;
            #pragma unroll
            for (int j = 0; j < 4; ++j) { pp[i][j] = __expf(sv[j] - mnew); rsum += pp[i][j]; }
            #pragma unroll
            for (int off = 1; off < 16; off <<= 1)
                rsum += __shfl_xor(rsum, off, 64);
            l_i[i] = l_i[i] * alpha + rsum;
            m_i[i] = mnew;
            #pragma unroll
            for (int jd = 0; jd < 8; ++jd) O[i][jd] *= alpha;
        }
        __syncthreads();   // B3: K reads done; safe to write P and stage V
        // write P (k-major, swizzled): chunk = 4 consecutive q for one k-row
        #pragma unroll
        for (int j = 0; j < 4; ++j) {
            int pk = (tx << 2) + j;
            *(float4*)&lds[PBASE + pk * 64 + ((ty ^ (pk & 15)) << 2)] =
                make_float4(pp[0][j], pp[1][j], pp[2][j], pp[3][j]);
        }
        // stage V (natural [k][128]) into [0,8192)
        #pragma unroll
        for (int i = 0; i < 8; ++i) {
            int cid = (i << 8) + tid;
            int k  = cid >> 5;
            int dc = cid & 31;
            int kg = (t << 6) + k;
            float4 vv = make_float4(0.f, 0.f, 0.f, 0.f);
            if (kg < L) {
                int pos = win_start + kg;
                const float* src = (pos < local_start)
                    ? (cache_v + (size_t)pos * DIM + hoff + (dc << 2))
                    : (vnew + (size_t)(pos - local_start) * DIM + hoff + (dc << 2));
                vv = *(const float4*)src;
            }
            *(float4*)&lds[(k << 7) + (dc << 2)] = vv;
        }
        __syncthreads();   // B4
        // O += P.V  (thread: 4q x 8d, d = tx*8..)
        #pragma unroll 8
        for (int kk = 0; kk < TK; ++kk) {
            float4 pv = *(const float4*)&lds[PBASE + kk * 64 + ((ty ^ (kk & 15)) << 2)];
            float4 v0 = *(const float4*)&lds[(kk << 7) + (tx << 3)];
            float4 v1 = *(const float4*)&lds[(kk << 7) + (tx << 3) + 4];
            float pr[4] = {pv.x, pv.y, pv.z, pv.w};
            float vr[8] = {v0.x, v0.y, v0.z, v0.w, v1.x, v1.y, v1.z, v1.w};
            #pragma unroll
            for (int i = 0; i < 4; ++i)
                #pragma unroll
                for (int jd = 0; jd < 8; ++jd)
                    O[i][jd] = fmaf(pr[i], vr[jd], O[i][jd]);
        }
    }

    #pragma unroll
    for (int i = 0; i < 4; ++i) {
        int q = q0 + (ty << 2) + i;
        if (q < S) {
            float inv = 1.0f / l_i[i];
            float* dst = obuf + (size_t)q * DIM + hoff + (tx << 3);
            *(float4*)&dst[0] = make_float4(O[i][0] * inv, O[i][1] * inv, O[i][2] * inv, O[i][3] * inv);
            *(float4*)&dst[4] = make_float4(O[i][4] * inv, O[i][5] * inv, O[i][6] * inv, O[i][7] * inv);
        }
    }
}

// ==================== launch ====================
extern "C" void kernel_launch(void* const* d_in, const int* in_sizes, int n_in,
                              void* d_out, int out_size, void* d_ws, size_t ws_size,
                              hipStream_t stream)
{
    const float* x       = (const float*)d_in[0];
    const float* theta   = (const float*)d_in[1];
    const float* cache_k = (const float*)d_in[2];
    const float* cache_v = (const float*)d_in[3];
    const float* wq = (const float*)d_in[4];
    const float* bq = (const float*)d_in[5];
    const float* wk = (const float*)d_in[6];
    const float* bk = (const float*)d_in[7];
    const float* wv = (const float*)d_in[8];
    const float* bv = (const float*)d_in[9];
    const float* wo = (const float*)d_in[10];
    const float* bo = (const float*)d_in[11];
    const float* gq = (const float*)d_in[12];
    const float* gk = (const float*)d_in[13];
    const int* p_gh = (const int*)d_in[15];
    const int* p_gw = (const int*)d_in[16];
    const int* p_cs = (const int*)d_in[17];
    const int* p_ge = (const int*)d_in[18];
    const int* p_le = (const int*)d_in[19];

    const int S = in_sizes[0] / DIM;   // B=1

    float* q_lin = (float*)d_ws;
    float* k_lin = q_lin + (size_t)S * DIM;
    float* v_lin = k_lin + (size_t)S * DIM;
    float* o_buf = v_lin + (size_t)S * DIM;

    dim3 blk(256);
    dim3 ggrid(DIM / BN, (S + BM - 1) / BM);
    gemm_bias_kernel<<<ggrid, blk, 0, stream>>>(x, wq, bq, q_lin, S, DIM, DIM);
    gemm_bias_kernel<<<ggrid, blk, 0, stream>>>(x, wk, bk, k_lin, S, DIM, DIM);
    gemm_bias_kernel<<<ggrid, blk, 0, stream>>>(x, wv, bv, v_lin, S, DIM, DIM);

    rmsnorm_rope_kernel<<<dim3(S, 2), blk, 0, stream>>>(q_lin, k_lin, gq, gk, theta,
                                                        p_gh, p_gw, p_cs, S);

    attn_kernel<<<dim3((S + TQ - 1) / TQ, NHEADS), blk, 0, stream>>>(
        q_lin, k_lin, v_lin, cache_k, cache_v, o_buf, p_cs, p_ge, p_le, S);

    gemm_bias_kernel<<<ggrid, blk, 0, stream>>>(o_buf, wo, bo, (float*)d_out, S, DIM, DIM);
}

// Round 3
// 2398.120 us; speedup vs baseline: 1.9655x; 1.9655x over previous
//
#include <hip/hip_runtime.h>

#define DIM 1536
#define NHEADS 12
#define HD 128
#define MAX_ATTN_WIN 5632
#define RMS_EPS 1e-6f
#define KWROWS 5632

typedef unsigned short ushortT;
typedef __bf16 bf16x8 __attribute__((ext_vector_type(8)));
typedef float f32x4 __attribute__((ext_vector_type(4)));
typedef ushortT ushx8 __attribute__((ext_vector_type(8)));

__device__ __forceinline__ ushortT bf16r(float x) {
    union { float f; unsigned u; } v; v.f = x;
    unsigned r = v.u + 0x7FFFu + ((v.u >> 16) & 1u);
    return (ushortT)(r >> 16);
}
__device__ __forceinline__ ushx8 pack8(float4 a, float4 b) {
    ushx8 u;
    u[0] = bf16r(a.x); u[1] = bf16r(a.y); u[2] = bf16r(a.z); u[3] = bf16r(a.w);
    u[4] = bf16r(b.x); u[5] = bf16r(b.y); u[6] = bf16r(b.z); u[7] = bf16r(b.w);
    return u;
}

// ==================== generic GEMM: C = A(MxK) * B(NxK)^T + bias ====================
#define BM 128
#define BN 128
#define BK 16

__global__ __launch_bounds__(256)
void gemm_bias_kernel(const float* __restrict__ A, const float* __restrict__ B,
                      const float* __restrict__ bias, float* __restrict__ C,
                      int M, int N, int K)
{
    __shared__ float As[BK][BM];
    __shared__ float Bs[BK][BN];
    const int tid = threadIdx.x;
    const int tx = tid & 15;
    const int ty = tid >> 4;
    const int m0 = blockIdx.y * BM;
    const int n0 = blockIdx.x * BN;

    float acc[8][8];
    #pragma unroll
    for (int i = 0; i < 8; ++i)
        #pragma unroll
        for (int j = 0; j < 8; ++j) acc[i][j] = 0.f;

    for (int k0 = 0; k0 < K; k0 += BK) {
        #pragma unroll
        for (int jj = 0; jj < 2; ++jj) {
            int lin = (jj << 8) + tid;
            int row = lin >> 2;
            int kq  = (lin & 3) << 2;
            int gm = m0 + row;
            float4 a = (gm < M) ? *(const float4*)&A[(size_t)gm * K + k0 + kq]
                                : make_float4(0.f, 0.f, 0.f, 0.f);
            As[kq + 0][row] = a.x; As[kq + 1][row] = a.y;
            As[kq + 2][row] = a.z; As[kq + 3][row] = a.w;
            float4 b = *(const float4*)&B[(size_t)(n0 + row) * K + k0 + kq];
            Bs[kq + 0][row] = b.x; Bs[kq + 1][row] = b.y;
            Bs[kq + 2][row] = b.z; Bs[kq + 3][row] = b.w;
        }
        __syncthreads();
        #pragma unroll
        for (int kk = 0; kk < BK; ++kk) {
            float4 a0 = *(const float4*)&As[kk][ty << 3];
            float4 a1 = *(const float4*)&As[kk][(ty << 3) + 4];
            float4 b0 = *(const float4*)&Bs[kk][tx << 3];
            float4 b1 = *(const float4*)&Bs[kk][(tx << 3) + 4];
            float av[8] = {a0.x, a0.y, a0.z, a0.w, a1.x, a1.y, a1.z, a1.w};
            float bv[8] = {b0.x, b0.y, b0.z, b0.w, b1.x, b1.y, b1.z, b1.w};
            #pragma unroll
            for (int i = 0; i < 8; ++i)
                #pragma unroll
                for (int j = 0; j < 8; ++j)
                    acc[i][j] = fmaf(av[i], bv[j], acc[i][j]);
        }
        __syncthreads();
    }

    #pragma unroll
    for (int i = 0; i < 8; ++i) {
        int gm = m0 + (ty << 3) + i;
        if (gm < M) {
            int gn = n0 + (tx << 3);
            float4 bb0 = *(const float4*)&bias[gn];
            float4 bb1 = *(const float4*)&bias[gn + 4];
            float4 o0 = make_float4(acc[i][0] + bb0.x, acc[i][1] + bb0.y,
                                    acc[i][2] + bb0.z, acc[i][3] + bb0.w);
            float4 o1 = make_float4(acc[i][4] + bb1.x, acc[i][5] + bb1.y,
                                    acc[i][6] + bb1.z, acc[i][7] + bb1.w);
            *(float4*)&C[(size_t)gm * N + gn]     = o0;
            *(float4*)&C[(size_t)gm * N + gn + 4] = o1;
        }
    }
}

// ==================== V GEMM with transposed-bf16 epilogue -> vw[h][d][vbase+s] ====================
__global__ __launch_bounds__(256)
void gemm_bias_vT_kernel(const float* __restrict__ A, const float* __restrict__ B,
                         const float* __restrict__ bias, ushortT* __restrict__ vw,
                         int M, int N, int K,
                         const int* __restrict__ p_cs, const int* __restrict__ p_ge,
                         const int* __restrict__ p_le)
{
    __shared__ float As[BK][BM];
    __shared__ float Bs[BK][BN];
    const int tid = threadIdx.x;
    const int tx = tid & 15;
    const int ty = tid >> 4;
    const int m0 = blockIdx.y * BM;
    const int n0 = blockIdx.x * BN;

    float acc[8][8];
    #pragma unroll
    for (int i = 0; i < 8; ++i)
        #pragma unroll
        for (int j = 0; j < 8; ++j) acc[i][j] = 0.f;

    for (int k0 = 0; k0 < K; k0 += BK) {
        #pragma unroll
        for (int jj = 0; jj < 2; ++jj) {
            int lin = (jj << 8) + tid;
            int row = lin >> 2;
            int kq  = (lin & 3) << 2;
            int gm = m0 + row;
            float4 a = (gm < M) ? *(const float4*)&A[(size_t)gm * K + k0 + kq]
                                : make_float4(0.f, 0.f, 0.f, 0.f);
            As[kq + 0][row] = a.x; As[kq + 1][row] = a.y;
            As[kq + 2][row] = a.z; As[kq + 3][row] = a.w;
            float4 b = *(const float4*)&B[(size_t)(n0 + row) * K + k0 + kq];
            Bs[kq + 0][row] = b.x; Bs[kq + 1][row] = b.y;
            Bs[kq + 2][row] = b.z; Bs[kq + 3][row] = b.w;
        }
        __syncthreads();
        #pragma unroll
        for (int kk = 0; kk < BK; ++kk) {
            float4 a0 = *(const float4*)&As[kk][ty << 3];
            float4 a1 = *(const float4*)&As[kk][(ty << 3) + 4];
            float4 b0 = *(const float4*)&Bs[kk][tx << 3];
            float4 b1 = *(const float4*)&Bs[kk][(tx << 3) + 4];
            float av[8] = {a0.x, a0.y, a0.z, a0.w, a1.x, a1.y, a1.z, a1.w};
            float bv[8] = {b0.x, b0.y, b0.z, b0.w, b1.x, b1.y, b1.z, b1.w};
            #pragma unroll
            for (int i = 0; i < 8; ++i)
                #pragma unroll
                for (int j = 0; j < 8; ++j)
                    acc[i][j] = fmaf(av[i], bv[j], acc[i][j]);
        }
        __syncthreads();
    }

    const int S = M;
    const int local_end = p_le[0] + (p_cs[0] + S) - p_ge[0];
    int win_start = local_end - MAX_ATTN_WIN; if (win_start < 0) win_start = 0;
    const int vbase = (local_end - S) - win_start;   // cache part length

    #pragma unroll
    for (int i = 0; i < 8; ++i) {
        int gm = m0 + (ty << 3) + i;
        if (gm < M) {
            #pragma unroll
            for (int j = 0; j < 8; ++j) {
                int gn = n0 + (tx << 3) + j;
                int h = gn >> 7, d = gn & 127;
                float val = acc[i][j] + bias[gn];
                vw[(size_t)h * (HD * KWROWS) + (size_t)d * KWROWS + vbase + gm] = bf16r(val);
            }
        }
    }
}

// ==================== fused RMSNorm + RoPE (in-place, one block per token) ====================
__global__ __launch_bounds__(256)
void rmsnorm_rope_kernel(float* __restrict__ qbuf, float* __restrict__ kbuf,
                         const float* __restrict__ gq, const float* __restrict__ gk,
                         const float* __restrict__ theta,
                         const int* __restrict__ p_gh, const int* __restrict__ p_gw,
                         const int* __restrict__ p_cs, int S)
{
    const int s = blockIdx.x;
    float* row = ((blockIdx.y == 0) ? qbuf : kbuf) + (size_t)s * DIM;
    const float* g = (blockIdx.y == 0) ? gq : gk;
    const int tid = threadIdx.x;

    float v[6];
    #pragma unroll
    for (int i = 0; i < 6; ++i) v[i] = row[tid * 6 + i];
    float ss = 0.f;
    #pragma unroll
    for (int i = 0; i < 6; ++i) ss += v[i] * v[i];
    #pragma unroll
    for (int off = 32; off > 0; off >>= 1) ss += __shfl_xor(ss, off, 64);

    __shared__ float red[4];
    if ((tid & 63) == 0) red[tid >> 6] = ss;
    __syncthreads();
    float tot = red[0] + red[1] + red[2] + red[3];
    float rs = rsqrtf(tot * (1.0f / DIM) + RMS_EPS);

    const int H = p_gh[0], W = p_gw[0];
    const int fs = p_cs[0] / (H * W);
    const int fr = s / (H * W);
    const int rem = s - fr * (H * W);
    const int hh = rem / W;
    const int ww = rem - hh * W;

    #pragma unroll
    for (int pi = 0; pi < 3; ++pi) {
        int p = tid * 3 + pi;
        int j = p & 63;
        float xr = v[pi * 2]     * rs * g[tid * 6 + pi * 2];
        float xi = v[pi * 2 + 1] * rs * g[tid * 6 + pi * 2 + 1];
        int rowi = (j < 22) ? (fs + fr) : ((j < 43) ? hh : ww);
        float ang = theta[rowi * 64 + j];
        float sn, cs;
        sincosf(ang, &sn, &cs);
        row[tid * 6 + pi * 2]     = xr * cs - xi * sn;
        row[tid * 6 + pi * 2 + 1] = xr * sn + xi * cs;
    }
}

// ==================== pack K window -> bf16 kw[h][pos][d] ====================
__global__ __launch_bounds__(256)
void pack_k_kernel(const float* __restrict__ cache_k, const float* __restrict__ k_lin,
                   ushortT* __restrict__ kw,
                   const int* __restrict__ p_cs, const int* __restrict__ p_ge,
                   const int* __restrict__ p_le, int S)
{
    const int kt = blockIdx.x, h = blockIdx.y;
    const int local_end = p_le[0] + (p_cs[0] + S) - p_ge[0];
    int win_start = local_end - MAX_ATTN_WIN; if (win_start < 0) win_start = 0;
    const int L = local_end - win_start;
    const int cpart = (local_end - S) - win_start;

    #pragma unroll
    for (int i = 0; i < 4; ++i) {
        int cid = (i << 8) + threadIdx.x;
        int r = cid >> 4, c = cid & 15;
        int pos = (kt << 6) + r;
        if (pos >= L) continue;
        const float* src = (pos < cpart)
            ? &cache_k[(size_t)(win_start + pos) * DIM + h * HD + (c << 3)]
            : &k_lin[(size_t)(pos - cpart) * DIM + h * HD + (c << 3)];
        float4 a = *(const float4*)src;
        float4 b = *(const float4*)(src + 4);
        *(ushx8*)&kw[(size_t)h * (KWROWS * HD) + (size_t)pos * HD + (c << 3)] = pack8(a, b);
    }
}

// ==================== pack cached V (transposed) -> bf16 vw[h][d][pos] ====================
__global__ __launch_bounds__(256)
void pack_v_cache_kernel(const float* __restrict__ cache_v, ushortT* __restrict__ vw,
                         const int* __restrict__ p_cs, const int* __restrict__ p_ge,
                         const int* __restrict__ p_le, int S)
{
    const int kt = blockIdx.x, h = blockIdx.y;
    const int local_end = p_le[0] + (p_cs[0] + S) - p_ge[0];
    int win_start = local_end - MAX_ATTN_WIN; if (win_start < 0) win_start = 0;
    const int cpart = (local_end - S) - win_start;
    if ((kt << 6) >= cpart) return;

    __shared__ float tile[64 * 132];
    #pragma unroll
    for (int i = 0; i < 8; ++i) {
        int cid = (i << 8) + threadIdx.x;
        int r = cid >> 5, fc = cid & 31;
        int pos = (kt << 6) + r;
        float4 vv = (pos < cpart)
            ? *(const float4*)&cache_v[(size_t)(win_start + pos) * DIM + h * HD + (fc << 2)]
            : make_float4(0.f, 0.f, 0.f, 0.f);
        *(float4*)&tile[r * 132 + (fc << 2)] = vv;
    }
    __syncthreads();
    #pragma unroll
    for (int i = 0; i < 4; ++i) {
        int cid = (i << 8) + threadIdx.x;
        int d = cid >> 3, kc = cid & 7;
        int kglob = (kt << 6) + (kc << 3);
        if (kglob >= cpart) continue;
        ushx8 u;
        #pragma unroll
        for (int j = 0; j < 8; ++j)
            u[j] = bf16r(tile[((kc << 3) + j) * 132 + d]);
        size_t base = (size_t)h * (HD * KWROWS) + (size_t)d * KWROWS + kglob;
        if (kglob + 8 <= cpart) {
            *(ushx8*)&vw[base] = u;
        } else {
            for (int j = 0; j < cpart - kglob; ++j) vw[base + j] = u[j];
        }
    }
}

// ==================== MFMA flash attention: Q-tile 128, K-tile 64 ====================
__global__ __launch_bounds__(256)
void attn_mfma_kernel(const float* __restrict__ q_lin,
                      const ushortT* __restrict__ kw, const ushortT* __restrict__ vw,
                      float* __restrict__ obuf,
                      const int* __restrict__ p_cs, const int* __restrict__ p_ge,
                      const int* __restrict__ p_le, int S)
{
    __shared__ ushortT sm[32768];      // 64 KB
    ushortT* Qs = sm;                  // [128][128] swizzled
    ushortT* KV = sm + 16384;          // Ks[64][128] / Vt[128][64]
    ushortT* Ps = sm + 24576;          // [128][64]

    const int tid = threadIdx.x;
    const int wid = tid >> 6, lane = tid & 63;
    const int lo = lane & 15, hi = lane >> 4;
    const int h = blockIdx.y;
    const int q0 = blockIdx.x << 7;

    const int local_end = p_le[0] + (p_cs[0] + S) - p_ge[0];
    int win_start = local_end - MAX_ATTN_WIN; if (win_start < 0) win_start = 0;
    const int L = local_end - win_start;
    const int ntiles = (L + 63) >> 6;

    // stage Q once: fp32 -> bf16, swizzled [row][chunk^(row&15)]
    #pragma unroll
    for (int i = 0; i < 8; ++i) {
        int cid = (i << 8) + tid;
        int r = cid >> 4, c = cid & 15;
        int q = q0 + r;
        ushx8 u;
        if (q < S) {
            const float* src = q_lin + (size_t)q * DIM + h * HD + (c << 3);
            float4 a = *(const float4*)src;
            float4 b = *(const float4*)(src + 4);
            u = pack8(a, b);
        } else {
            #pragma unroll
            for (int j = 0; j < 8; ++j) u[j] = 0;
        }
        *(ushx8*)&Qs[r * 128 + ((c ^ (r & 15)) << 3)] = u;
    }

    f32x4 Oa[2][8];
    float m_r[2][4], l_r[2][4];
    #pragma unroll
    for (int mt = 0; mt < 2; ++mt) {
        #pragma unroll
        for (int nto = 0; nto < 8; ++nto) Oa[mt][nto] = (f32x4)(0.f);
        #pragma unroll
        for (int r = 0; r < 4; ++r) { m_r[mt][r] = -1e30f; l_r[mt][r] = 0.f; }
    }

    const size_t kwh = (size_t)h * (KWROWS * HD);
    const size_t vwh = (size_t)h * (HD * KWROWS);
    const float scale = 0.08838834764831845f;

    for (int t = 0; t < ntiles; ++t) {
        __syncthreads();                                     // B1: prior PV reads done
        // stage K tile (bf16 copy, swizzled)
        #pragma unroll
        for (int i = 0; i < 4; ++i) {
            int cid = (i << 8) + tid;
            int r = cid >> 4, c = cid & 15;
            int pos = (t << 6) + r;
            ushx8 u;
            if (pos < L) {
                u = *(const ushx8*)&kw[kwh + (size_t)pos * HD + (c << 3)];
            } else {
                #pragma unroll
                for (int j = 0; j < 8; ++j) u[j] = 0;
            }
            *(ushx8*)&KV[r * 128 + ((c ^ (r & 15)) << 3)] = u;
        }
        __syncthreads();                                     // B2: K (and Q) visible

        // ---- S = Q K^T ----
        bf16x8 aF[2][4];
        #pragma unroll
        for (int mt = 0; mt < 2; ++mt) {
            int r = (wid << 5) + (mt << 4) + lo;
            #pragma unroll
            for (int ks = 0; ks < 4; ++ks)
                aF[mt][ks] = *(const bf16x8*)&Qs[r * 128 + ((((ks << 2) + hi) ^ (r & 15)) << 3)];
        }
        f32x4 Sa[2][4];
        #pragma unroll
        for (int mt = 0; mt < 2; ++mt)
            #pragma unroll
            for (int nt = 0; nt < 4; ++nt) Sa[mt][nt] = (f32x4)(0.f);
        #pragma unroll
        for (int nt = 0; nt < 4; ++nt) {
            int kr = (nt << 4) + lo;
            #pragma unroll
            for (int ks = 0; ks < 4; ++ks) {
                bf16x8 bF = *(const bf16x8*)&KV[kr * 128 + ((((ks << 2) + hi) ^ (kr & 15)) << 3)];
                Sa[0][nt] = __builtin_amdgcn_mfma_f32_16x16x32_bf16(aF[0][ks], bF, Sa[0][nt], 0, 0, 0);
                Sa[1][nt] = __builtin_amdgcn_mfma_f32_16x16x32_bf16(aF[1][ks], bF, Sa[1][nt], 0, 0, 0);
            }
        }

        // ---- online softmax (rows: 32*wid + 16*mt + 4*hi + reg; col: 16*nt + lo) ----
        const bool tail = (((t + 1) << 6) > L);
        #pragma unroll
        for (int mt = 0; mt < 2; ++mt) {
            #pragma unroll
            for (int reg = 0; reg < 4; ++reg) {
                float sv[4];
                #pragma unroll
                for (int nt = 0; nt < 4; ++nt) {
                    sv[nt] = Sa[mt][nt][reg] * scale;
                    if (tail) {
                        int kg = (t << 6) + (nt << 4) + lo;
                        if (kg >= L) sv[nt] = -1e30f;
                    }
                }
                float mx = fmaxf(fmaxf(sv[0], sv[1]), fmaxf(sv[2], sv[3]));
                #pragma unroll
                for (int off = 1; off < 16; off <<= 1)
                    mx = fmaxf(mx, __shfl_xor(mx, off, 64));
                float mnew = fmaxf(m_r[mt][reg], mx);
                float al = __expf(m_r[mt][reg] - mnew);
                m_r[mt][reg] = mnew;
                float rsum = 0.f;
                #pragma unroll
                for (int nt = 0; nt < 4; ++nt) {
                    float pv = __expf(sv[nt] - mnew);
                    Sa[mt][nt][reg] = pv;          // reuse Sa as P
                    rsum += pv;
                }
                #pragma unroll
                for (int off = 1; off < 16; off <<= 1)
                    rsum += __shfl_xor(rsum, off, 64);
                l_r[mt][reg] = l_r[mt][reg] * al + rsum;
                #pragma unroll
                for (int nto = 0; nto < 8; ++nto) Oa[mt][nto][reg] *= al;
            }
        }
        __syncthreads();                                     // B3: QK LDS reads done

        // write P (bf16, [q][key] swizzled) + stage V transposed tile
        #pragma unroll
        for (int mt = 0; mt < 2; ++mt)
            #pragma unroll
            for (int nt = 0; nt < 4; ++nt)
                #pragma unroll
                for (int reg = 0; reg < 4; ++reg) {
                    int r = (wid << 5) + (mt << 4) + (hi << 2) + reg;
                    int col = (nt << 4) + lo;
                    Ps[r * 64 + (((col >> 3) ^ (r & 7)) << 3) + (col & 7)] = bf16r(Sa[mt][nt][reg]);
                }
        #pragma unroll
        for (int i = 0; i < 4; ++i) {
            int cid = (i << 8) + tid;
            int d = cid >> 3, c = cid & 7;
            int kbase = (t << 6) + (c << 3);
            ushx8 u;
            if (kbase < L) {
                u = *(const ushx8*)&vw[vwh + (size_t)d * KWROWS + kbase];
            } else {
                #pragma unroll
                for (int j = 0; j < 8; ++j) u[j] = 0;
            }
            *(ushx8*)&KV[d * 64 + ((c ^ (d & 7)) << 3)] = u;
        }
        __syncthreads();                                     // B4: P + V staged

        // ---- O += P V ----
        bf16x8 pF[2][2];
        #pragma unroll
        for (int mt = 0; mt < 2; ++mt) {
            int r = (wid << 5) + (mt << 4) + lo;
            #pragma unroll
            for (int ks = 0; ks < 2; ++ks)
                pF[mt][ks] = *(const bf16x8*)&Ps[r * 64 + ((((ks << 2) + hi) ^ (r & 7)) << 3)];
        }
        #pragma unroll
        for (int nto = 0; nto < 8; ++nto) {
            int d = (nto << 4) + lo;
            #pragma unroll
            for (int ks = 0; ks < 2; ++ks) {
                bf16x8 vF = *(const bf16x8*)&KV[d * 64 + ((((ks << 2) + hi) ^ (d & 7)) << 3)];
                Oa[0][nto] = __builtin_amdgcn_mfma_f32_16x16x32_bf16(pF[0][ks], vF, Oa[0][nto], 0, 0, 0);
                Oa[1][nto] = __builtin_amdgcn_mfma_f32_16x16x32_bf16(pF[1][ks], vF, Oa[1][nto], 0, 0, 0);
            }
        }
    }

    // epilogue: O / l -> obuf fp32
    #pragma unroll
    for (int mt = 0; mt < 2; ++mt)
        #pragma unroll
        for (int reg = 0; reg < 4; ++reg) {
            int q = q0 + (wid << 5) + (mt << 4) + (hi << 2) + reg;
            if (q < S) {
                float inv = 1.f / l_r[mt][reg];
                #pragma unroll
                for (int nto = 0; nto < 8; ++nto)
                    obuf[(size_t)q * DIM + h * HD + (nto << 4) + lo] = Oa[mt][nto][reg] * inv;
            }
        }
}

// ==================== launch ====================
extern "C" void kernel_launch(void* const* d_in, const int* in_sizes, int n_in,
                              void* d_out, int out_size, void* d_ws, size_t ws_size,
                              hipStream_t stream)
{
    const float* x       = (const float*)d_in[0];
    const float* theta   = (const float*)d_in[1];
    const float* cache_k = (const float*)d_in[2];
    const float* cache_v = (const float*)d_in[3];
    const float* wq = (const float*)d_in[4];
    const float* bq = (const float*)d_in[5];
    const float* wk = (const float*)d_in[6];
    const float* bk = (const float*)d_in[7];
    const float* wv = (const float*)d_in[8];
    const float* bv = (const float*)d_in[9];
    const float* wo = (const float*)d_in[10];
    const float* bo = (const float*)d_in[11];
    const float* gq = (const float*)d_in[12];
    const float* gk = (const float*)d_in[13];
    const int* p_gh = (const int*)d_in[15];
    const int* p_gw = (const int*)d_in[16];
    const int* p_cs = (const int*)d_in[17];
    const int* p_ge = (const int*)d_in[18];
    const int* p_le = (const int*)d_in[19];

    const int S = in_sizes[0] / DIM;

    float* q_lin = (float*)d_ws;
    float* k_lin = q_lin + (size_t)S * DIM;
    float* o_buf = k_lin;                               // alias: k_lin dead after pack_k
    ushortT* kw = (ushortT*)(k_lin + (size_t)S * DIM);
    ushortT* vw = kw + (size_t)NHEADS * KWROWS * HD;

    dim3 blk(256);
    dim3 ggrid(DIM / BN, (S + BM - 1) / BM);
    gemm_bias_kernel<<<ggrid, blk, 0, stream>>>(x, wq, bq, q_lin, S, DIM, DIM);
    gemm_bias_kernel<<<ggrid, blk, 0, stream>>>(x, wk, bk, k_lin, S, DIM, DIM);
    gemm_bias_vT_kernel<<<ggrid, blk, 0, stream>>>(x, wv, bv, vw, S, DIM, DIM, p_cs, p_ge, p_le);

    rmsnorm_rope_kernel<<<dim3(S, 2), blk, 0, stream>>>(q_lin, k_lin, gq, gk, theta,
                                                        p_gh, p_gw, p_cs, S);

    pack_k_kernel<<<dim3(KWROWS / 64, NHEADS), blk, 0, stream>>>(cache_k, k_lin, kw,
                                                                 p_cs, p_ge, p_le, S);
    pack_v_cache_kernel<<<dim3(KWROWS / 64, NHEADS), blk, 0, stream>>>(cache_v, vw,
                                                                       p_cs, p_ge, p_le, S);

    attn_mfma_kernel<<<dim3((S + 127) / 128, NHEADS), blk, 0, stream>>>(
        q_lin, kw, vw, o_buf, p_cs, p_ge, p_le, S);

    gemm_bias_kernel<<<ggrid, blk, 0, stream>>>(o_buf, wo, bo, (float*)d_out, S, DIM, DIM);
}

// Round 4
// 884.545 us; speedup vs baseline: 5.3288x; 2.7111x over previous
//
#include <hip/hip_runtime.h>

#define DIM 1536
#define NHEADS 12
#define HD 128
#define MAX_ATTN_WIN 5632
#define RMS_EPS 1e-6f
#define KWROWS 5632

typedef unsigned short ushortT;
typedef __bf16 bf16x8 __attribute__((ext_vector_type(8)));
typedef float f32x4 __attribute__((ext_vector_type(4)));
typedef ushortT ushx8 __attribute__((ext_vector_type(8)));

__device__ __forceinline__ ushortT bf16r(float x) {
    union { float f; unsigned u; } v; v.f = x;
    unsigned r = v.u + 0x7FFFu + ((v.u >> 16) & 1u);
    return (ushortT)(r >> 16);
}
__device__ __forceinline__ ushx8 pack8(float4 a, float4 b) {
    ushx8 u;
    u[0] = bf16r(a.x); u[1] = bf16r(a.y); u[2] = bf16r(a.z); u[3] = bf16r(a.w);
    u[4] = bf16r(b.x); u[5] = bf16r(b.y); u[6] = bf16r(b.z); u[7] = bf16r(b.w);
    return u;
}

// ============ split-bf16 GEMM: C = A(MxK) * B(NxK)^T + bias ============
// A ~= Ah+Al, B ~= Bh+Bl (bf16); C ~= Ah*Bh + Al*Bh + Ah*Bl  (error ~2^-17)
// Tile 64x128, BK=32, 4 waves as 2x2, each wave 32x64 (2x4 16x16 frags).
// LDS stride 40 (pad 32->40) makes frag-read banks 2-way (free).
#define GSTR 40

template<int MODE>   // 0: fp32 C + bias.  1: bf16 transposed into vw[h][d][vbase+m]
__global__ __launch_bounds__(256)
void gemm_split_kernel(const float* __restrict__ A, const float* __restrict__ B,
                       const float* __restrict__ bias, float* __restrict__ C,
                       ushortT* __restrict__ vwout, int M, int N, int K,
                       const int* __restrict__ p_cs, const int* __restrict__ p_ge,
                       const int* __restrict__ p_le)
{
    __shared__ ushortT Ah[64 * GSTR];
    __shared__ ushortT Al[64 * GSTR];
    __shared__ ushortT Bh[128 * GSTR];
    __shared__ ushortT Bl[128 * GSTR];

    const int tid = threadIdx.x;
    const int wid = tid >> 6, lane = tid & 63;
    const int lo = lane & 15, hi = lane >> 4;
    const int wm = wid >> 1, wn = wid & 1;
    const int m0 = blockIdx.y * 64, n0 = blockIdx.x * 128;

    f32x4 acc[2][4];
    #pragma unroll
    for (int i = 0; i < 2; ++i)
        #pragma unroll
        for (int j = 0; j < 4; ++j) acc[i][j] = (f32x4)(0.f);

    const int arow = tid >> 2, akq = (tid & 3) << 3;   // A: 64 rows x 32k, 8 el/thread
    const int brow = tid >> 1, bkq = (tid & 1) << 4;   // B: 128 rows x 32k, 16 el/thread
    const bool avalid = (m0 + arow) < M;

    for (int k0 = 0; k0 < K; k0 += 32) {
        __syncthreads();                       // prior frag reads done
        {   // stage A (fp32 -> hi/lo bf16)
            float4 a0 = make_float4(0.f, 0.f, 0.f, 0.f), a1 = a0;
            if (avalid) {
                const float* p = A + (size_t)(m0 + arow) * K + k0 + akq;
                a0 = *(const float4*)p;
                a1 = *(const float4*)(p + 4);
            }
            float xs[8] = {a0.x, a0.y, a0.z, a0.w, a1.x, a1.y, a1.z, a1.w};
            ushx8 uh, ul;
            #pragma unroll
            for (int j = 0; j < 8; ++j) {
                ushortT hh = bf16r(xs[j]);
                union { unsigned u; float f; } w; w.u = ((unsigned)hh) << 16;
                uh[j] = hh;
                ul[j] = bf16r(xs[j] - w.f);
            }
            *(ushx8*)&Ah[arow * GSTR + akq] = uh;
            *(ushx8*)&Al[arow * GSTR + akq] = ul;
        }
        {   // stage B
            const float* p = B + (size_t)(n0 + brow) * K + k0 + bkq;
            float4 b0 = *(const float4*)p;
            float4 b1 = *(const float4*)(p + 4);
            float4 b2 = *(const float4*)(p + 8);
            float4 b3 = *(const float4*)(p + 12);
            float ys[16] = {b0.x, b0.y, b0.z, b0.w, b1.x, b1.y, b1.z, b1.w,
                            b2.x, b2.y, b2.z, b2.w, b3.x, b3.y, b3.z, b3.w};
            ushx8 uh0, ul0, uh1, ul1;
            #pragma unroll
            for (int j = 0; j < 8; ++j) {
                ushortT hh = bf16r(ys[j]);
                union { unsigned u; float f; } w; w.u = ((unsigned)hh) << 16;
                uh0[j] = hh; ul0[j] = bf16r(ys[j] - w.f);
            }
            #pragma unroll
            for (int j = 0; j < 8; ++j) {
                ushortT hh = bf16r(ys[8 + j]);
                union { unsigned u; float f; } w; w.u = ((unsigned)hh) << 16;
                uh1[j] = hh; ul1[j] = bf16r(ys[8 + j] - w.f);
            }
            *(ushx8*)&Bh[brow * GSTR + bkq]     = uh0;
            *(ushx8*)&Bh[brow * GSTR + bkq + 8] = uh1;
            *(ushx8*)&Bl[brow * GSTR + bkq]     = ul0;
            *(ushx8*)&Bl[brow * GSTR + bkq + 8] = ul1;
        }
        __syncthreads();

        bf16x8 aH[2], aL[2];
        #pragma unroll
        for (int mf = 0; mf < 2; ++mf) {
            int r = (wm << 5) + (mf << 4) + lo;
            aH[mf] = *(const bf16x8*)&Ah[r * GSTR + (hi << 3)];
            aL[mf] = *(const bf16x8*)&Al[r * GSTR + (hi << 3)];
        }
        #pragma unroll
        for (int nf = 0; nf < 4; ++nf) {
            int rn = (wn << 6) + (nf << 4) + lo;
            bf16x8 bH = *(const bf16x8*)&Bh[rn * GSTR + (hi << 3)];
            bf16x8 bL = *(const bf16x8*)&Bl[rn * GSTR + (hi << 3)];
            #pragma unroll
            for (int mf = 0; mf < 2; ++mf) {
                acc[mf][nf] = __builtin_amdgcn_mfma_f32_16x16x32_bf16(aH[mf], bH, acc[mf][nf], 0, 0, 0);
                acc[mf][nf] = __builtin_amdgcn_mfma_f32_16x16x32_bf16(aL[mf], bH, acc[mf][nf], 0, 0, 0);
                acc[mf][nf] = __builtin_amdgcn_mfma_f32_16x16x32_bf16(aH[mf], bL, acc[mf][nf], 0, 0, 0);
            }
        }
    }

    if (MODE == 0) {
        #pragma unroll
        for (int mf = 0; mf < 2; ++mf) {
            #pragma unroll
            for (int reg = 0; reg < 4; ++reg) {
                int gm = m0 + (wm << 5) + (mf << 4) + (hi << 2) + reg;
                if (gm < M) {
                    #pragma unroll
                    for (int nf = 0; nf < 4; ++nf) {
                        int gn = n0 + (wn << 6) + (nf << 4) + lo;
                        C[(size_t)gm * N + gn] = acc[mf][nf][reg] + bias[gn];
                    }
                }
            }
        }
    } else {
        const int S = M;
        const int local_end = p_le[0] + (p_cs[0] + S) - p_ge[0];
        int win_start = local_end - MAX_ATTN_WIN; if (win_start < 0) win_start = 0;
        const int vbase = (local_end - S) - win_start;
        #pragma unroll
        for (int mf = 0; mf < 2; ++mf) {
            #pragma unroll
            for (int reg = 0; reg < 4; ++reg) {
                int gm = m0 + (wm << 5) + (mf << 4) + (hi << 2) + reg;
                if (gm < M) {
                    #pragma unroll
                    for (int nf = 0; nf < 4; ++nf) {
                        int gn = n0 + (wn << 6) + (nf << 4) + lo;
                        int h2 = gn >> 7, d = gn & 127;
                        vwout[(size_t)h2 * (HD * KWROWS) + (size_t)d * KWROWS + vbase + gm] =
                            bf16r(acc[mf][nf][reg] + bias[gn]);
                    }
                }
            }
        }
    }
}

// ============ fused RMSNorm + RoPE (in-place, one block per token) ============
__global__ __launch_bounds__(256)
void rmsnorm_rope_kernel(float* __restrict__ qbuf, float* __restrict__ kbuf,
                         const float* __restrict__ gq, const float* __restrict__ gk,
                         const float* __restrict__ theta,
                         const int* __restrict__ p_gh, const int* __restrict__ p_gw,
                         const int* __restrict__ p_cs, int S)
{
    const int s = blockIdx.x;
    float* row = ((blockIdx.y == 0) ? qbuf : kbuf) + (size_t)s * DIM;
    const float* g = (blockIdx.y == 0) ? gq : gk;
    const int tid = threadIdx.x;

    float v[6];
    #pragma unroll
    for (int i = 0; i < 6; ++i) v[i] = row[tid * 6 + i];
    float ss = 0.f;
    #pragma unroll
    for (int i = 0; i < 6; ++i) ss += v[i] * v[i];
    #pragma unroll
    for (int off = 32; off > 0; off >>= 1) ss += __shfl_xor(ss, off, 64);

    __shared__ float red[4];
    if ((tid & 63) == 0) red[tid >> 6] = ss;
    __syncthreads();
    float tot = red[0] + red[1] + red[2] + red[3];
    float rs = rsqrtf(tot * (1.0f / DIM) + RMS_EPS);

    const int H = p_gh[0], W = p_gw[0];
    const int fs = p_cs[0] / (H * W);
    const int fr = s / (H * W);
    const int rem = s - fr * (H * W);
    const int hh = rem / W;
    const int ww = rem - hh * W;

    #pragma unroll
    for (int pi = 0; pi < 3; ++pi) {
        int p = tid * 3 + pi;
        int j = p & 63;
        float xr = v[pi * 2]     * rs * g[tid * 6 + pi * 2];
        float xi = v[pi * 2 + 1] * rs * g[tid * 6 + pi * 2 + 1];
        int rowi = (j < 22) ? (fs + fr) : ((j < 43) ? hh : ww);
        float ang = theta[rowi * 64 + j];
        float sn, cs;
        sincosf(ang, &sn, &cs);
        row[tid * 6 + pi * 2]     = xr * cs - xi * sn;
        row[tid * 6 + pi * 2 + 1] = xr * sn + xi * cs;
    }
}

// ============ pack K window -> bf16 kw[h][pos][d] ============
__global__ __launch_bounds__(256)
void pack_k_kernel(const float* __restrict__ cache_k, const float* __restrict__ k_lin,
                   ushortT* __restrict__ kw,
                   const int* __restrict__ p_cs, const int* __restrict__ p_ge,
                   const int* __restrict__ p_le, int S)
{
    const int kt = blockIdx.x, h = blockIdx.y;
    const int local_end = p_le[0] + (p_cs[0] + S) - p_ge[0];
    int win_start = local_end - MAX_ATTN_WIN; if (win_start < 0) win_start = 0;
    const int L = local_end - win_start;
    const int cpart = (local_end - S) - win_start;

    #pragma unroll
    for (int i = 0; i < 4; ++i) {
        int cid = (i << 8) + threadIdx.x;
        int r = cid >> 4, c = cid & 15;
        int pos = (kt << 6) + r;
        if (pos >= L) continue;
        const float* src = (pos < cpart)
            ? &cache_k[(size_t)(win_start + pos) * DIM + h * HD + (c << 3)]
            : &k_lin[(size_t)(pos - cpart) * DIM + h * HD + (c << 3)];
        float4 a = *(const float4*)src;
        float4 b = *(const float4*)(src + 4);
        *(ushx8*)&kw[(size_t)h * (KWROWS * HD) + (size_t)pos * HD + (c << 3)] = pack8(a, b);
    }
}

// ============ pack cached V (transposed) -> bf16 vw[h][d][pos] ============
__global__ __launch_bounds__(256)
void pack_v_cache_kernel(const float* __restrict__ cache_v, ushortT* __restrict__ vw,
                         const int* __restrict__ p_cs, const int* __restrict__ p_ge,
                         const int* __restrict__ p_le, int S)
{
    const int kt = blockIdx.x, h = blockIdx.y;
    const int local_end = p_le[0] + (p_cs[0] + S) - p_ge[0];
    int win_start = local_end - MAX_ATTN_WIN; if (win_start < 0) win_start = 0;
    const int cpart = (local_end - S) - win_start;
    if ((kt << 6) >= cpart) return;

    __shared__ float tile[64 * 132];
    #pragma unroll
    for (int i = 0; i < 8; ++i) {
        int cid = (i << 8) + threadIdx.x;
        int r = cid >> 5, fc = cid & 31;
        int pos = (kt << 6) + r;
        float4 vv = (pos < cpart)
            ? *(const float4*)&cache_v[(size_t)(win_start + pos) * DIM + h * HD + (fc << 2)]
            : make_float4(0.f, 0.f, 0.f, 0.f);
        *(float4*)&tile[r * 132 + (fc << 2)] = vv;
    }
    __syncthreads();
    #pragma unroll
    for (int i = 0; i < 4; ++i) {
        int cid = (i << 8) + threadIdx.x;
        int d = cid >> 3, kc = cid & 7;
        int kglob = (kt << 6) + (kc << 3);
        if (kglob >= cpart) continue;
        ushx8 u;
        #pragma unroll
        for (int j = 0; j < 8; ++j)
            u[j] = bf16r(tile[((kc << 3) + j) * 132 + d]);
        size_t base = (size_t)h * (HD * KWROWS) + (size_t)d * KWROWS + kglob;
        if (kglob + 8 <= cpart) {
            *(ushx8*)&vw[base] = u;
        } else {
            for (int j = 0; j < cpart - kglob; ++j) vw[base + j] = u[j];
        }
    }
}

// ============ MFMA flash attention v2: Q-tile 64 (regs), K-tile 64, 40 KB LDS ============
// 588 blocks; 2 barriers/tile; wave-private P round-trip (no barrier);
// fixed-max softmax (M=20) -> no running max / no O rescale.
__global__ __launch_bounds__(256, 3)
void attn_mfma2_kernel(const float* __restrict__ q_lin,
                       const ushortT* __restrict__ kw, const ushortT* __restrict__ vw,
                       float* __restrict__ obuf,
                       const int* __restrict__ p_cs, const int* __restrict__ p_ge,
                       const int* __restrict__ p_le, int S)
{
    __shared__ ushortT sm[20480];      // 40 KB
    ushortT* Ks = sm;                  // [64][128] swizzled (16 KB)
    ushortT* Vs = sm + 8192;           // [128][64] transposed swizzled (16 KB)
    ushortT* Ps = sm + 16384;          // 4 waves x [16][64] swizzled (8 KB)

    const int tid = threadIdx.x;
    const int wid = tid >> 6, lane = tid & 63;
    const int lo = lane & 15, hi = lane >> 4;
    const int h = blockIdx.y;
    const int q0 = blockIdx.x << 6;

    const int local_end = p_le[0] + (p_cs[0] + S) - p_ge[0];
    int win_start = local_end - MAX_ATTN_WIN; if (win_start < 0) win_start = 0;
    const int L = local_end - win_start;
    const int ntiles = (L + 63) >> 6;

    // Q A-frags in registers: m = lo (q row = q0 + wid*16 + lo), k = ks*32 + hi*8 + j
    bf16x8 aQ[4];
    {
        int q = q0 + (wid << 4) + lo;
        if (q < S) {
            const float* qp = q_lin + (size_t)q * DIM + h * HD + (hi << 3);
            #pragma unroll
            for (int ks = 0; ks < 4; ++ks) {
                float4 a = *(const float4*)&qp[ks * 32];
                float4 b = *(const float4*)&qp[ks * 32 + 4];
                ushx8 u = pack8(a, b);
                aQ[ks] = *(bf16x8*)&u;
            }
        } else {
            ushx8 z;
            #pragma unroll
            for (int j = 0; j < 8; ++j) z[j] = 0;
            #pragma unroll
            for (int ks = 0; ks < 4; ++ks) aQ[ks] = *(bf16x8*)&z;
        }
    }

    f32x4 Oa[8];
    float lsum[4];
    #pragma unroll
    for (int i = 0; i < 8; ++i) Oa[i] = (f32x4)(0.f);
    #pragma unroll
    for (int i = 0; i < 4; ++i) lsum[i] = 0.f;

    const size_t kwh = (size_t)h * (KWROWS * HD);
    const size_t vwh = (size_t)h * (HD * KWROWS);
    const float scale = 0.08838834764831845f;   // 1/sqrt(128)
    const int pbase = wid << 10;                // wave-private 1024-el P region

    for (int t = 0; t < ntiles; ++t) {
        __syncthreads();                         // prior tile's Ks/Vs reads done
        // stage K tile [64][128]
        #pragma unroll
        for (int i = 0; i < 4; ++i) {
            int cid = (i << 8) + tid;
            int r = cid >> 4, c = cid & 15;
            int pos = (t << 6) + r;
            ushx8 u;
            if (pos < L) {
                u = *(const ushx8*)&kw[kwh + (size_t)pos * HD + (c << 3)];
            } else {
                #pragma unroll
                for (int j = 0; j < 8; ++j) u[j] = 0;
            }
            *(ushx8*)&Ks[r * 128 + ((c ^ (r & 15)) << 3)] = u;
        }
        // stage V tile transposed [128][64]
        #pragma unroll
        for (int i = 0; i < 4; ++i) {
            int cid = (i << 8) + tid;
            int d = cid >> 3, c = cid & 7;
            int kb = (t << 6) + (c << 3);
            ushx8 u;
            if (kb < L) {
                u = *(const ushx8*)&vw[vwh + (size_t)d * KWROWS + kb];
            } else {
                #pragma unroll
                for (int j = 0; j < 8; ++j) u[j] = 0;
            }
            *(ushx8*)&Vs[d * 64 + ((c ^ (d & 7)) << 3)] = u;
        }
        __syncthreads();                         // staged

        // ---- S = Q K^T ----
        f32x4 Sa[4];
        #pragma unroll
        for (int nt = 0; nt < 4; ++nt) Sa[nt] = (f32x4)(0.f);
        #pragma unroll
        for (int nt = 0; nt < 4; ++nt) {
            int kr = (nt << 4) + lo;
            #pragma unroll
            for (int ks = 0; ks < 4; ++ks) {
                bf16x8 bF = *(const bf16x8*)&Ks[kr * 128 + ((((ks << 2) + hi) ^ (kr & 15)) << 3)];
                Sa[nt] = __builtin_amdgcn_mfma_f32_16x16x32_bf16(aQ[ks], bF, Sa[nt], 0, 0, 0);
            }
        }

        // ---- fixed-max softmax: p = exp(s*scale - 20); accumulate l per lane ----
        const bool tail = (((t + 1) << 6) > L);
        #pragma unroll
        for (int nt = 0; nt < 4; ++nt) {
            #pragma unroll
            for (int reg = 0; reg < 4; ++reg) {
                float sv = Sa[nt][reg] * scale - 20.f;
                if (tail) {
                    int kg = (t << 6) + (nt << 4) + lo;
                    if (kg >= L) sv = -1e30f;
                }
                float p = __expf(sv);
                lsum[reg] += p;
                Sa[nt][reg] = p;
            }
        }

        // ---- P -> wave-private LDS (C-layout -> A-layout); same-wave DS ordered ----
        #pragma unroll
        for (int nt = 0; nt < 4; ++nt) {
            #pragma unroll
            for (int reg = 0; reg < 4; ++reg) {
                int r = (hi << 2) + reg;
                int cc = (nt << 1) + (lo >> 3);
                Ps[pbase + (r << 6) + ((cc ^ (r & 7)) << 3) + (lo & 7)] = bf16r(Sa[nt][reg]);
            }
        }
        bf16x8 pF[2];
        #pragma unroll
        for (int ks = 0; ks < 2; ++ks)
            pF[ks] = *(const bf16x8*)&Ps[pbase + (lo << 6) + ((((ks << 2) + hi) ^ (lo & 7)) << 3)];

        // ---- O += P V ----
        #pragma unroll
        for (int nto = 0; nto < 8; ++nto) {
            int d = (nto << 4) + lo;
            #pragma unroll
            for (int ks = 0; ks < 2; ++ks) {
                bf16x8 vF = *(const bf16x8*)&Vs[d * 64 + ((((ks << 2) + hi) ^ (d & 7)) << 3)];
                Oa[nto] = __builtin_amdgcn_mfma_f32_16x16x32_bf16(pF[ks], vF, Oa[nto], 0, 0, 0);
            }
        }
    }

    // final l: reduce across the 16 column-lanes
    #pragma unroll
    for (int reg = 0; reg < 4; ++reg) {
        #pragma unroll
        for (int off = 1; off < 16; off <<= 1)
            lsum[reg] += __shfl_xor(lsum[reg], off, 64);
    }
    #pragma unroll
    for (int reg = 0; reg < 4; ++reg) {
        int q = q0 + (wid << 4) + (hi << 2) + reg;
        if (q < S) {
            float inv = 1.f / lsum[reg];
            #pragma unroll
            for (int nto = 0; nto < 8; ++nto)
                obuf[(size_t)q * DIM + h * HD + (nto << 4) + lo] = Oa[nto][reg] * inv;
        }
    }
}

// ==================== launch ====================
extern "C" void kernel_launch(void* const* d_in, const int* in_sizes, int n_in,
                              void* d_out, int out_size, void* d_ws, size_t ws_size,
                              hipStream_t stream)
{
    const float* x       = (const float*)d_in[0];
    const float* theta   = (const float*)d_in[1];
    const float* cache_k = (const float*)d_in[2];
    const float* cache_v = (const float*)d_in[3];
    const float* wq = (const float*)d_in[4];
    const float* bq = (const float*)d_in[5];
    const float* wk = (const float*)d_in[6];
    const float* bk = (const float*)d_in[7];
    const float* wv = (const float*)d_in[8];
    const float* bv = (const float*)d_in[9];
    const float* wo = (const float*)d_in[10];
    const float* bo = (const float*)d_in[11];
    const float* gq = (const float*)d_in[12];
    const float* gk = (const float*)d_in[13];
    const int* p_gh = (const int*)d_in[15];
    const int* p_gw = (const int*)d_in[16];
    const int* p_cs = (const int*)d_in[17];
    const int* p_ge = (const int*)d_in[18];
    const int* p_le = (const int*)d_in[19];

    const int S = in_sizes[0] / DIM;

    float* q_lin = (float*)d_ws;
    float* k_lin = q_lin + (size_t)S * DIM;
    float* o_buf = k_lin;                               // alias: k_lin dead after pack_k
    ushortT* kw = (ushortT*)(k_lin + (size_t)S * DIM);
    ushortT* vw = kw + (size_t)NHEADS * KWROWS * HD;

    dim3 blk(256);
    dim3 sgrid(DIM / 128, (S + 63) / 64);   // 12 x 49

    gemm_split_kernel<0><<<sgrid, blk, 0, stream>>>(x, wq, bq, q_lin, nullptr,
                                                    S, DIM, DIM, p_cs, p_ge, p_le);
    gemm_split_kernel<0><<<sgrid, blk, 0, stream>>>(x, wk, bk, k_lin, nullptr,
                                                    S, DIM, DIM, p_cs, p_ge, p_le);
    gemm_split_kernel<1><<<sgrid, blk, 0, stream>>>(x, wv, bv, nullptr, vw,
                                                    S, DIM, DIM, p_cs, p_ge, p_le);

    rmsnorm_rope_kernel<<<dim3(S, 2), blk, 0, stream>>>(q_lin, k_lin, gq, gk, theta,
                                                        p_gh, p_gw, p_cs, S);

    pack_k_kernel<<<dim3(KWROWS / 64, NHEADS), blk, 0, stream>>>(cache_k, k_lin, kw,
                                                                 p_cs, p_ge, p_le, S);
    pack_v_cache_kernel<<<dim3(KWROWS / 64, NHEADS), blk, 0, stream>>>(cache_v, vw,
                                                                       p_cs, p_ge, p_le, S);

    attn_mfma2_kernel<<<dim3((S + 63) / 64, NHEADS), blk, 0, stream>>>(
        q_lin, kw, vw, o_buf, p_cs, p_ge, p_le, S);

    gemm_split_kernel<0><<<sgrid, blk, 0, stream>>>(o_buf, wo, bo, (float*)d_out, nullptr,
                                                    S, DIM, DIM, p_cs, p_ge, p_le);
}